// Round 1
// baseline (38891.882 us; speedup 1.0000x reference)
//
#include <hip/hip_runtime.h>
#include <hip/hip_cooperative_groups.h>
#include <stddef.h>
#include <math.h>

namespace cg = cooperative_groups;

static constexpr int B = 64, P = 196, ED = 2048, AD = 512, DD = 512, E = 300, V = 1000, T = 96, TD = 95;
static constexpr int KX = E + ED;      // 2348
static constexpr int KTOT = KX + DD;   // 2860
static constexpr int NS = 4;           // K-splits for gates GEMM
static constexpr int KPER2 = KTOT / NS; // 715
static constexpr int NG = 4 * DD;      // 2048

// d_out layout (all float32): predictions (B,TD,V), caps (B,T), decode_lengths (B),
// alphas (B,TD,P), sort_ind (B)
static constexpr size_t POFF   = 0;
static constexpr size_t CAPOFF = (size_t)B * TD * V;
static constexpr size_t DLOFF  = CAPOFF + (size_t)B * T;
static constexpr size_t AOFF   = DLOFF + B;
static constexpr size_t SOFF   = AOFF + (size_t)B * TD * P;

__device__ __forceinline__ float sigm(float x) { return 1.0f / (1.0f + expf(-x)); }

// ---------------------------------------------------------------------------
// K0: stable descending sort by length + gather caps + write int-ish outputs
// ---------------------------------------------------------------------------
__global__ __launch_bounds__(64) void k_sort(const int* __restrict__ lens,
                                             const int* __restrict__ caps_in,
                                             int* __restrict__ sidx,
                                             int* __restrict__ dlen,
                                             int* __restrict__ caps_s,
                                             float* __restrict__ out) {
    __shared__ int sl[B];
    __shared__ int ss[B];
    int i = threadIdx.x;
    sl[i] = lens[i];
    __syncthreads();
    int li = sl[i];
    int r = 0;
    for (int j = 0; j < B; j++) {
        int lj = sl[j];
        r += (lj > li) || (lj == li && j < i);
    }
    ss[r] = i;
    sidx[r] = i;
    dlen[r] = li - 1;
    out[DLOFF + r] = (float)(li - 1);
    out[SOFF + r] = (float)i;
    __syncthreads();
    for (int idx = i; idx < B * T; idx += B) {
        int b = idx / T, tt = idx % T;
        int v = caps_in[ss[b] * T + tt];
        caps_s[idx] = v;
        out[CAPOFF + idx] = (float)v;
    }
}

// ---------------------------------------------------------------------------
// K1: mean over P of sorted encoder_out -> mean_eo (B, ED)
// ---------------------------------------------------------------------------
__global__ __launch_bounds__(256) void k_mean(const float* __restrict__ eo,
                                              const int* __restrict__ sidx,
                                              float* __restrict__ mean_eo) {
    int b = blockIdx.y;
    int d = blockIdx.x * 256 + threadIdx.x;
    const float* base = eo + ((size_t)sidx[b] * P) * ED + d;
    float s = 0.f;
    for (int p = 0; p < P; p++) s += base[(size_t)p * ED];
    mean_eo[(size_t)b * ED + d] = s * (1.0f / (float)P);
}

// ---------------------------------------------------------------------------
// K2: h0/c0 init; seeds the h-rows of xT (K-major x buffer)
// ---------------------------------------------------------------------------
__global__ __launch_bounds__(256) void k_init(const float* __restrict__ mean_eo,
                                              const float* __restrict__ Wh, const float* __restrict__ bh,
                                              const float* __restrict__ Wc, const float* __restrict__ bc,
                                              float* __restrict__ h0, float* __restrict__ c0,
                                              float* __restrict__ xT) {
    int idx = blockIdx.x * 256 + threadIdx.x;  // B*DD
    int b = idx >> 9, j = idx & 511;
    const float* m = mean_eo + (size_t)b * ED;
    float ah = bh[j], ac = bc[j];
    for (int k = 0; k < ED; k++) {
        float mv = m[k];
        ah += mv * Wh[(size_t)k * DD + j];
        ac += mv * Wc[(size_t)k * DD + j];
    }
    h0[idx] = ah;
    c0[idx] = ac;
    xT[(size_t)(KX + j) * B + b] = ah;
}

// ---------------------------------------------------------------------------
// K3: att1[m,n] = eo_sorted[m,:] @ W_enc_att[:,n] + b   (row-major, B*P x AD)
// ---------------------------------------------------------------------------
__global__ __launch_bounds__(256) void k_att1(const float* __restrict__ eo,
                                              const float* __restrict__ W,
                                              const float* __restrict__ bias,
                                              const int* __restrict__ sidx,
                                              float* __restrict__ att1) {
    int m0 = blockIdx.x * 64, n0 = blockIdx.y * 64;
    __shared__ float sA[16][68];
    __shared__ float sB[16][68];
    int tid = threadIdx.x;
    int tx = tid & 15, ty = tid >> 4;
    float acc[4][4] = {};

    int la_m = tid >> 2;
    int la_k = (tid & 3) * 4;
    int lb_k = tid >> 4;
    int lb_n = (tid & 15) * 4;

    int mA = m0 + la_m;
    int bA = mA / P, pA = mA % P;
    const float* arow = eo + ((size_t)sidx[bA] * P + pA) * ED;

    for (int k0 = 0; k0 < ED; k0 += 16) {
        float4 av = *(const float4*)(arow + k0 + la_k);
        sA[la_k + 0][la_m] = av.x;
        sA[la_k + 1][la_m] = av.y;
        sA[la_k + 2][la_m] = av.z;
        sA[la_k + 3][la_m] = av.w;
        float4 bv = *(const float4*)(W + (size_t)(k0 + lb_k) * AD + n0 + lb_n);
        *(float4*)&sB[lb_k][lb_n] = bv;
        __syncthreads();
#pragma unroll
        for (int kk = 0; kk < 16; kk++) {
            float4 a4 = *(const float4*)&sA[kk][ty * 4];
            float4 b4 = *(const float4*)&sB[kk][tx * 4];
            float av_[4] = {a4.x, a4.y, a4.z, a4.w};
            float bv_[4] = {b4.x, b4.y, b4.z, b4.w};
#pragma unroll
            for (int i = 0; i < 4; i++)
#pragma unroll
                for (int j = 0; j < 4; j++) acc[i][j] += av_[i] * bv_[j];
        }
        __syncthreads();
    }
#pragma unroll
    for (int i = 0; i < 4; i++) {
        int m = m0 + ty * 4 + i;
        int n = n0 + tx * 4;
        float4 o;
        o.x = acc[i][0] + bias[n + 0];
        o.y = acc[i][1] + bias[n + 1];
        o.z = acc[i][2] + bias[n + 2];
        o.w = acc[i][3] + bias[n + 3];
        *(float4*)(att1 + (size_t)m * AD + n) = o;
    }
}

// ---------------------------------------------------------------------------
// k_steps: persistent cooperative kernel running all TD timesteps.
// grid 256 x 512 threads (1 block/CU). 5 grid.sync() per step.
//   P1: att2 (h@Wda+b) + fg (sigm(h@Wfb+b)) as 80 GEMM-tile blocks (32 cols
//       each, kA1-style LDS inner loop widened to 512 thr) + 5 emb-gather blocks
//   P2: per-b relu-dot + softmax -> alpha (64 blocks, 8 waves each)
//   P3: awe = eo . alpha ; xg = fg*awe -> xT rows [E,E+ED)  (256 blocks)
//   P4: gates partial GEMM, 4 K-splits x 64 N-tiles, direct loads, no LDS
//   P5: reduce partials + LSTM cell + mask blend (64 blocks)
// ---------------------------------------------------------------------------
__global__ __launch_bounds__(512, 2) void k_steps(
    const float* __restrict__ eo, const int* __restrict__ sidx,
    const int* __restrict__ dlen, const int* __restrict__ caps_s,
    const float* __restrict__ emb,
    const float* __restrict__ Wda, const float* __restrict__ bda,
    const float* __restrict__ Wfb, const float* __restrict__ bfb,
    const float* __restrict__ wfull, const float* __restrict__ bfull,
    const float* __restrict__ att1,
    const float* __restrict__ Wih, const float* __restrict__ Whh,
    const float* __restrict__ bih, const float* __restrict__ bhh,
    const float* __restrict__ h0, float* __restrict__ cb0, float* __restrict__ cb1,
    float* __restrict__ att2g, float* __restrict__ fg, float* __restrict__ xT,
    float* __restrict__ part, float* __restrict__ alphaW,
    float* __restrict__ hseq, float* __restrict__ out)
{
    cg::grid_group grid = cg::this_grid();
    const int bid = blockIdx.x;
    const int tid = threadIdx.x;

    __shared__ float sH[16][68];
    __shared__ float sW[16][36];
    __shared__ float sa2[AD];
    __shared__ float swf[AD];
    __shared__ float se[P];
    __shared__ float red[512];
    __shared__ float sal[P];

#pragma unroll 1
    for (int t = 0; t < TD; t++) {
        const float* hprev = (t == 0) ? h0 : (hseq + (size_t)(t - 1) * B * DD);

        // ---------------- P1: att2 + fg + emb gather --------------------
        if (bid < 80) {
            int n0 = bid * 32;                 // combined col space [att2 512 | fg 2048]
            bool is_att = (n0 < AD);
            const float* W = is_att ? Wda : Wfb;
            int ld = is_att ? AD : ED;
            int colb = is_att ? n0 : (n0 - AD);
            int tb = tid & 15, tn = tid >> 4;  // tb: 16 groups of 4 b; tn: 32 cols
            float a0 = 0.f, a1 = 0.f, a2 = 0.f, a3 = 0.f;
            for (int k0 = 0; k0 < DD; k0 += 16) {
                if (tid < 256) {
                    int b = tid >> 2, q = tid & 3;
                    float4 hv = *(const float4*)(hprev + (size_t)b * DD + k0 + q * 4);
                    sH[q * 4 + 0][b] = hv.x;
                    sH[q * 4 + 1][b] = hv.y;
                    sH[q * 4 + 2][b] = hv.z;
                    sH[q * 4 + 3][b] = hv.w;
                }
                if (tid < 128) {
                    int kk = tid >> 3, nn = (tid & 7) * 4;
                    *(float4*)&sW[kk][nn] = *(const float4*)(W + (size_t)(k0 + kk) * ld + colb + nn);
                }
                __syncthreads();
#pragma unroll
                for (int kk = 0; kk < 16; kk++) {
                    float4 hv = *(const float4*)&sH[kk][tb * 4];
                    float wv = sW[kk][tn];
                    a0 += hv.x * wv; a1 += hv.y * wv; a2 += hv.z * wv; a3 += hv.w * wv;
                }
                __syncthreads();
            }
            float accv[4] = {a0, a1, a2, a3};
            int n = n0 + tn;
            if (is_att) {
                float bv = bda[n];
#pragma unroll
                for (int i = 0; i < 4; i++)
                    att2g[(size_t)(tb * 4 + i) * AD + n] = accv[i] + bv;
            } else {
                int d = n - AD;
                float bv = bfb[d];
#pragma unroll
                for (int i = 0; i < 4; i++)
                    fg[(size_t)(tb * 4 + i) * ED + d] = sigm(accv[i] + bv);
            }
        } else if (bid < 85) {
            int k0 = (bid - 80) * 60;
            for (int l = tid; l < 60 * 64; l += 512) {
                int r = l >> 6, b = l & 63;
                int k = k0 + r;
                int cap = caps_s[b * T + t];
                xT[(size_t)k * B + b] = emb[(size_t)cap * E + k];
            }
        }
        grid.sync();

        // ---------------- P2: per-b softmax -> alpha --------------------
        if (bid < B) {
            int b = bid;
            sa2[tid] = att2g[(size_t)b * AD + tid];
            swf[tid] = wfull[tid];
            __syncthreads();
            int wv_ = tid >> 6, lane = tid & 63;
            float bf0 = bfull[0];
            for (int p = wv_; p < P; p += 8) {
                const float* row = att1 + ((size_t)b * P + p) * AD + lane * 8;
                float4 u0 = *(const float4*)row;
                float4 u1 = *(const float4*)(row + 4);
                float4 s0 = *(const float4*)&sa2[lane * 8];
                float4 s1 = *(const float4*)&sa2[lane * 8 + 4];
                float4 w0 = *(const float4*)&swf[lane * 8];
                float4 w1 = *(const float4*)&swf[lane * 8 + 4];
                float acc = fmaxf(u0.x + s0.x, 0.f) * w0.x + fmaxf(u0.y + s0.y, 0.f) * w0.y +
                            fmaxf(u0.z + s0.z, 0.f) * w0.z + fmaxf(u0.w + s0.w, 0.f) * w0.w +
                            fmaxf(u1.x + s1.x, 0.f) * w1.x + fmaxf(u1.y + s1.y, 0.f) * w1.y +
                            fmaxf(u1.z + s1.z, 0.f) * w1.z + fmaxf(u1.w + s1.w, 0.f) * w1.w;
#pragma unroll
                for (int mm = 32; mm >= 1; mm >>= 1) acc += __shfl_xor(acc, mm, 64);
                if (lane == 0) se[p] = acc + bf0;
            }
            __syncthreads();
            red[tid] = (tid < P) ? se[tid] : -1e30f;
            __syncthreads();
            for (int s = 256; s > 0; s >>= 1) {
                if (tid < s) red[tid] = fmaxf(red[tid], red[tid + s]);
                __syncthreads();
            }
            float mx = red[0];
            __syncthreads();
            float ex = (tid < P) ? expf(se[tid] - mx) : 0.f;
            red[tid] = ex;
            __syncthreads();
            for (int s = 256; s > 0; s >>= 1) {
                if (tid < s) red[tid] += red[tid + s];
                __syncthreads();
            }
            float inv = 1.0f / red[0];
            if (tid < P) {
                float a = ex * inv;
                alphaW[(size_t)b * P + tid] = a;
                float m = (dlen[b] > t) ? 1.f : 0.f;
                out[AOFF + ((size_t)b * TD + t) * P + tid] = a * m;
            }
        }
        grid.sync();

        // ---------------- P3: awe + xg -> xT rows [E, E+ED) -------------
        {
            int b = bid >> 2, ch = bid & 3;
            if (tid < P) sal[tid] = alphaW[(size_t)b * P + tid];
            __syncthreads();
            int d = ch * 512 + tid;
            const float* base = eo + ((size_t)sidx[b] * P) * ED + d;
            float aw = 0.f;
#pragma unroll 4
            for (int p = 0; p < P; p++) aw += base[(size_t)p * ED] * sal[p];
            xT[(size_t)(E + d) * B + b] = fg[(size_t)b * ED + d] * aw;
            __syncthreads();  // protect sal before next phase reuse patterns
        }
        grid.sync();

        // ---------------- P4: gates partial GEMM ------------------------
        {
            int ks = bid & 3, nt = bid >> 2;
            int n0 = nt * 32;
            int tb = tid & 15, tn = tid >> 4;
            int n = n0 + tn;
            float a0 = 0.f, a1 = 0.f, a2 = 0.f, a3 = 0.f;
            int klo = ks * KPER2, khi = klo + KPER2;
            int kmid = (khi < KX) ? khi : KX;
            for (int k = klo; k < kmid; k++) {
                float4 xv = *(const float4*)&xT[(size_t)k * B + tb * 4];
                float wv = Wih[(size_t)k * NG + n];
                a0 += xv.x * wv; a1 += xv.y * wv; a2 += xv.z * wv; a3 += xv.w * wv;
            }
            for (int k = (klo > KX ? klo : KX); k < khi; k++) {
                float4 xv = *(const float4*)&xT[(size_t)k * B + tb * 4];
                float wv = Whh[(size_t)(k - KX) * NG + n];
                a0 += xv.x * wv; a1 += xv.y * wv; a2 += xv.z * wv; a3 += xv.w * wv;
            }
            float* pr = part + (size_t)ks * B * NG + n;
            pr[(size_t)(tb * 4 + 0) * NG] = a0;
            pr[(size_t)(tb * 4 + 1) * NG] = a1;
            pr[(size_t)(tb * 4 + 2) * NG] = a2;
            pr[(size_t)(tb * 4 + 3) * NG] = a3;
        }
        grid.sync();

        // ---------------- P5: reduce + LSTM cell ------------------------
        if (bid < B) {
            int b = bid, j = tid;
            const float* cc = (t & 1) ? cb1 : cb0;
            float* cn = (t & 1) ? cb0 : cb1;
            float gi = bih[j] + bhh[j];
            float gf = bih[DD + j] + bhh[DD + j];
            float gg = bih[2 * DD + j] + bhh[2 * DD + j];
            float go = bih[3 * DD + j] + bhh[3 * DD + j];
#pragma unroll
            for (int s = 0; s < NS; s++) {
                const float* pr = part + ((size_t)s * B + b) * NG;
                gi += pr[j];
                gf += pr[DD + j];
                gg += pr[2 * DD + j];
                go += pr[3 * DD + j];
            }
            float cold = cc[(size_t)b * DD + j], hold = hprev[(size_t)b * DD + j];
            float cnew = sigm(gf) * cold + sigm(gi) * tanhf(gg);
            float hnew = sigm(go) * tanhf(cnew);
            bool m = dlen[b] > t;
            float h2 = m ? hnew : hold;
            float c2 = m ? cnew : cold;
            hseq[(size_t)t * B * DD + (size_t)b * DD + j] = h2;
            cn[(size_t)b * DD + j] = c2;
            xT[(size_t)(KX + j) * B + b] = h2;
        }
        grid.sync();
    }
}

// ---------------------------------------------------------------------------
// K4: batched preds GEMM: out[b,t,v] = mask * (hseq[t,b,:]@Wfc + bfc)
// ---------------------------------------------------------------------------
__global__ __launch_bounds__(256) void k_predsall(const float* __restrict__ hseq,
                                                  const float* __restrict__ Wfc,
                                                  const float* __restrict__ bfc,
                                                  const int* __restrict__ dlen,
                                                  float* __restrict__ out) {
    int t = blockIdx.x;
    int n0 = blockIdx.y * 64;
    int tid = threadIdx.x;
    int tx = tid & 15, ty = tid >> 4;
    __shared__ float sA[16][68];
    __shared__ float sB[16][68];
    float acc[4][4] = {};
    const float* A = hseq + (size_t)t * B * DD;

    for (int k0 = 0; k0 < DD; k0 += 16) {
        {
            int b = tid >> 2, q = tid & 3;
            float4 hv = *(const float4*)(A + (size_t)b * DD + k0 + q * 4);
            sA[q * 4 + 0][b] = hv.x;
            sA[q * 4 + 1][b] = hv.y;
            sA[q * 4 + 2][b] = hv.z;
            sA[q * 4 + 3][b] = hv.w;
        }
        {
            int kk = tid >> 4, nn = (tid & 15) * 4;
            int c = n0 + nn;
            const float* wrow = Wfc + (size_t)(k0 + kk) * V;
            float4 wv;
            if (c + 3 < V) wv = *(const float4*)(wrow + c);
            else {
                wv.x = (c + 0 < V) ? wrow[c + 0] : 0.f;
                wv.y = (c + 1 < V) ? wrow[c + 1] : 0.f;
                wv.z = (c + 2 < V) ? wrow[c + 2] : 0.f;
                wv.w = (c + 3 < V) ? wrow[c + 3] : 0.f;
            }
            *(float4*)&sB[kk][nn] = wv;
        }
        __syncthreads();
#pragma unroll
        for (int kk = 0; kk < 16; kk++) {
            float4 a4 = *(const float4*)&sA[kk][ty * 4];
            float4 b4 = *(const float4*)&sB[kk][tx * 4];
            float av_[4] = {a4.x, a4.y, a4.z, a4.w};
            float bv_[4] = {b4.x, b4.y, b4.z, b4.w};
#pragma unroll
            for (int i = 0; i < 4; i++)
#pragma unroll
                for (int j = 0; j < 4; j++) acc[i][j] += av_[i] * bv_[j];
        }
        __syncthreads();
    }
#pragma unroll
    for (int i = 0; i < 4; i++) {
        int b = ty * 4 + i;
        bool m = dlen[b] > t;
#pragma unroll
        for (int j = 0; j < 4; j++) {
            int n = n0 + tx * 4 + j;
            if (n < V)
                out[POFF + ((size_t)b * TD + t) * V + n] = m ? (acc[i][j] + bfc[n]) : 0.f;
        }
    }
}

// ---------------------------------------------------------------------------
extern "C" void kernel_launch(void* const* d_in, const int* in_sizes, int n_in,
                              void* d_out, int out_size, void* d_ws, size_t ws_size,
                              hipStream_t stream) {
    const float* eo    = (const float*)d_in[0];
    const int*   caps  = (const int*)d_in[1];
    const int*   lens  = (const int*)d_in[2];
    const float* emb   = (const float*)d_in[3];
    const float* Wea   = (const float*)d_in[4];
    const float* bea   = (const float*)d_in[5];
    const float* Wda   = (const float*)d_in[6];
    const float* bda   = (const float*)d_in[7];
    const float* wfull = (const float*)d_in[8];
    const float* bfull = (const float*)d_in[9];
    const float* Wih_  = (const float*)d_in[10];
    const float* bih_  = (const float*)d_in[11];
    const float* Wic   = (const float*)d_in[12];
    const float* bic   = (const float*)d_in[13];
    const float* Wfb   = (const float*)d_in[14];
    const float* bfb   = (const float*)d_in[15];
    const float* Wih   = (const float*)d_in[16];
    const float* bih   = (const float*)d_in[17];
    const float* Whh   = (const float*)d_in[18];
    const float* bhh   = (const float*)d_in[19];
    const float* Wfc   = (const float*)d_in[20];
    const float* bfc   = (const float*)d_in[21];
    float* out = (float*)d_out;

    char* w = (char*)d_ws;
    auto carve = [&](size_t bytes) -> void* {
        void* p = (void*)w;
        w += (bytes + 255) & ~(size_t)255;
        return p;
    };
    int* sidx      = (int*)carve(B * 4);
    int* dlen      = (int*)carve(B * 4);
    int* caps_s    = (int*)carve((size_t)B * T * 4);
    float* mean_eo = (float*)carve((size_t)B * ED * 4);
    float* h0      = (float*)carve((size_t)B * DD * 4);
    float* cb0     = (float*)carve((size_t)B * DD * 4);
    float* cb1     = (float*)carve((size_t)B * DD * 4);
    float* att1    = (float*)carve((size_t)B * P * AD * 4);
    float* alphaW  = (float*)carve((size_t)B * P * 4);
    float* att2g   = (float*)carve((size_t)B * AD * 4);
    float* fg      = (float*)carve((size_t)B * ED * 4);
    float* xT      = (float*)carve((size_t)KTOT * B * 4);
    float* part    = (float*)carve((size_t)NS * B * NG * 4);
    float* hseq    = (float*)carve((size_t)TD * B * DD * 4);

    k_sort<<<1, 64, 0, stream>>>(lens, caps, sidx, dlen, caps_s, out);
    k_mean<<<dim3(ED / 256, B), 256, 0, stream>>>(eo, sidx, mean_eo);
    k_init<<<(B * DD) / 256, 256, 0, stream>>>(mean_eo, Wih_, bih_, Wic, bic, h0, cb0, xT);
    k_att1<<<dim3((B * P) / 64, AD / 64), 256, 0, stream>>>(eo, Wea, bea, sidx, att1);

    void* kargs[] = {
        (void*)&eo, (void*)&sidx, (void*)&dlen, (void*)&caps_s, (void*)&emb,
        (void*)&Wda, (void*)&bda, (void*)&Wfb, (void*)&bfb,
        (void*)&wfull, (void*)&bfull, (void*)&att1,
        (void*)&Wih, (void*)&Whh, (void*)&bih, (void*)&bhh,
        (void*)&h0, (void*)&cb0, (void*)&cb1,
        (void*)&att2g, (void*)&fg, (void*)&xT, (void*)&part, (void*)&alphaW,
        (void*)&hseq, (void*)&out
    };
    hipLaunchCooperativeKernel((void*)k_steps, dim3(256), dim3(512), kargs, 0, stream);

    k_predsall<<<dim3(TD, 16), 256, 0, stream>>>(hseq, Wfc, bfc, dlen, out);
}

// Round 2
// 17753.192 us; speedup vs baseline: 2.1907x; 2.1907x over previous
//
#include <hip/hip_runtime.h>
#include <stddef.h>
#include <math.h>

static constexpr int B = 64, P = 196, ED = 2048, AD = 512, DD = 512, E = 300, V = 1000, T = 96, TD = 95;
static constexpr int KX = E + ED;      // 2348
static constexpr int KTOT = KX + DD;   // 2860
static constexpr int KSPLIT = 8;
static constexpr int KPER = 368;       // 23 tiles of 16; 8*368 = 2944 >= 2860
static constexpr int NG = 4 * DD;      // 2048

// d_out layout (all float32): predictions (B,TD,V), caps (B,T), decode_lengths (B),
// alphas (B,TD,P), sort_ind (B)
static constexpr size_t POFF   = 0;
static constexpr size_t CAPOFF = (size_t)B * TD * V;
static constexpr size_t DLOFF  = CAPOFF + (size_t)B * T;
static constexpr size_t AOFF   = DLOFF + B;
static constexpr size_t SOFF   = AOFF + (size_t)B * TD * P;

__device__ __forceinline__ float sigm(float x) { return 1.0f / (1.0f + expf(-x)); }

// ---------------------------------------------------------------------------
// K0: stable descending sort by length + gather caps + write int-ish outputs
// ---------------------------------------------------------------------------
__global__ __launch_bounds__(64) void k_sort(const int* __restrict__ lens,
                                             const int* __restrict__ caps_in,
                                             int* __restrict__ sidx,
                                             int* __restrict__ dlen,
                                             int* __restrict__ caps_s,
                                             float* __restrict__ out) {
    __shared__ int sl[B];
    __shared__ int ss[B];
    int i = threadIdx.x;
    sl[i] = lens[i];
    __syncthreads();
    int li = sl[i];
    int r = 0;
    for (int j = 0; j < B; j++) {
        int lj = sl[j];
        r += (lj > li) || (lj == li && j < i);
    }
    ss[r] = i;
    sidx[r] = i;
    dlen[r] = li - 1;
    out[DLOFF + r] = (float)(li - 1);
    out[SOFF + r] = (float)i;
    __syncthreads();
    for (int idx = i; idx < B * T; idx += B) {
        int b = idx / T, tt = idx % T;
        int v = caps_in[ss[b] * T + tt];
        caps_s[idx] = v;
        out[CAPOFF + idx] = (float)v;
    }
}

// ---------------------------------------------------------------------------
// K1: mean over P of sorted encoder_out -> mean_eo (B, ED)
// ---------------------------------------------------------------------------
__global__ __launch_bounds__(256) void k_mean(const float* __restrict__ eo,
                                              const int* __restrict__ sidx,
                                              float* __restrict__ mean_eo) {
    int b = blockIdx.y;
    int d = blockIdx.x * 256 + threadIdx.x;
    const float* base = eo + ((size_t)sidx[b] * P) * ED + d;
    float s = 0.f;
    for (int p = 0; p < P; p++) s += base[(size_t)p * ED];
    mean_eo[(size_t)b * ED + d] = s * (1.0f / (float)P);
}

// ---------------------------------------------------------------------------
// K2: h0/c0 init; seeds the h-rows of xT (K-major x buffer)
// ---------------------------------------------------------------------------
__global__ __launch_bounds__(256) void k_init(const float* __restrict__ mean_eo,
                                              const float* __restrict__ Wh, const float* __restrict__ bh,
                                              const float* __restrict__ Wc, const float* __restrict__ bc,
                                              float* __restrict__ h0, float* __restrict__ c0,
                                              float* __restrict__ xT) {
    int idx = blockIdx.x * 256 + threadIdx.x;  // B*DD
    int b = idx >> 9, j = idx & 511;
    const float* m = mean_eo + (size_t)b * ED;
    float ah = bh[j], ac = bc[j];
    for (int k = 0; k < ED; k++) {
        float mv = m[k];
        ah += mv * Wh[(size_t)k * DD + j];
        ac += mv * Wc[(size_t)k * DD + j];
    }
    h0[idx] = ah;
    c0[idx] = ac;
    xT[(size_t)(KX + j) * B + b] = ah;
}

// ---------------------------------------------------------------------------
// K3: att1[m,n] = eo_sorted[m,:] @ W_enc_att[:,n] + b   (row-major, B*P x AD)
// ---------------------------------------------------------------------------
__global__ __launch_bounds__(256) void k_att1(const float* __restrict__ eo,
                                              const float* __restrict__ W,
                                              const float* __restrict__ bias,
                                              const int* __restrict__ sidx,
                                              float* __restrict__ att1) {
    int m0 = blockIdx.x * 64, n0 = blockIdx.y * 64;
    __shared__ float sA[16][68];
    __shared__ float sB[16][68];
    int tid = threadIdx.x;
    int tx = tid & 15, ty = tid >> 4;
    float acc[4][4] = {};

    int la_m = tid >> 2;
    int la_k = (tid & 3) * 4;
    int lb_k = tid >> 4;
    int lb_n = (tid & 15) * 4;

    int mA = m0 + la_m;
    int bA = mA / P, pA = mA % P;
    const float* arow = eo + ((size_t)sidx[bA] * P + pA) * ED;

    for (int k0 = 0; k0 < ED; k0 += 16) {
        float4 av = *(const float4*)(arow + k0 + la_k);
        sA[la_k + 0][la_m] = av.x;
        sA[la_k + 1][la_m] = av.y;
        sA[la_k + 2][la_m] = av.z;
        sA[la_k + 3][la_m] = av.w;
        float4 bv = *(const float4*)(W + (size_t)(k0 + lb_k) * AD + n0 + lb_n);
        *(float4*)&sB[lb_k][lb_n] = bv;
        __syncthreads();
#pragma unroll
        for (int kk = 0; kk < 16; kk++) {
            float4 a4 = *(const float4*)&sA[kk][ty * 4];
            float4 b4 = *(const float4*)&sB[kk][tx * 4];
            float av_[4] = {a4.x, a4.y, a4.z, a4.w};
            float bv_[4] = {b4.x, b4.y, b4.z, b4.w};
#pragma unroll
            for (int i = 0; i < 4; i++)
#pragma unroll
                for (int j = 0; j < 4; j++) acc[i][j] += av_[i] * bv_[j];
        }
        __syncthreads();
    }
#pragma unroll
    for (int i = 0; i < 4; i++) {
        int m = m0 + ty * 4 + i;
        int n = n0 + tx * 4;
        float4 o;
        o.x = acc[i][0] + bias[n + 0];
        o.y = acc[i][1] + bias[n + 1];
        o.z = acc[i][2] + bias[n + 2];
        o.w = acc[i][3] + bias[n + 3];
        *(float4*)(att1 + (size_t)m * AD + n) = o;
    }
}

// ---------------------------------------------------------------------------
// kA1: blocks [0,80): B-tiled small GEMMs off hprev — each weight read ONCE.
//        n in [0,512):   att2[b][n]  = hprev@Wda + bda          (no act)
//        n in [512,2560): fg[b][n-512] = sigm(hprev@Wfb + bfb)
//      blocks [80,85): gather emb(t) into xT rows [0,300).
// ---------------------------------------------------------------------------
__global__ __launch_bounds__(256) void kA1(const float* __restrict__ hprev,
                                           const float* __restrict__ Wda, const float* __restrict__ bda,
                                           const float* __restrict__ Wfb, const float* __restrict__ bfb,
                                           const float* __restrict__ emb,
                                           const int* __restrict__ caps_s,
                                           float* __restrict__ att2g,
                                           float* __restrict__ fg,
                                           float* __restrict__ xT, int t) {
    int bx = blockIdx.x;
    int tid = threadIdx.x;
    if (bx >= 80) {
        // emb gather: 60 k-rows per block
        int k0 = (bx - 80) * 60;
        for (int l = tid; l < 60 * 64; l += 256) {
            int r = l >> 6, b = l & 63;
            int k = k0 + r;
            int cap = caps_s[b * T + t];
            xT[(size_t)k * B + b] = emb[(size_t)cap * E + k];
        }
        return;
    }
    int n0 = bx * 32;
    bool is_att = (n0 < AD);
    __shared__ float sH[16][68];
    __shared__ float sW[16][36];
    float acc[4][2] = {};
    int tb = tid & 15, tn = tid >> 4;

    for (int k0 = 0; k0 < DD; k0 += 16) {
        {
            int b = tid >> 2, q = tid & 3;
            float4 hv = *(const float4*)(hprev + (size_t)b * DD + k0 + q * 4);
            sH[q * 4 + 0][b] = hv.x;
            sH[q * 4 + 1][b] = hv.y;
            sH[q * 4 + 2][b] = hv.z;
            sH[q * 4 + 3][b] = hv.w;
        }
        if (tid < 128) {
            int kk = tid >> 3, nn = (tid & 7) * 4;
            float4 wv;
            if (is_att) wv = *(const float4*)(Wda + (size_t)(k0 + kk) * AD + n0 + nn);
            else        wv = *(const float4*)(Wfb + (size_t)(k0 + kk) * ED + (n0 - AD) + nn);
            *(float4*)&sW[kk][nn] = wv;
        }
        __syncthreads();
#pragma unroll
        for (int kk = 0; kk < 16; kk++) {
            float4 hv = *(const float4*)&sH[kk][tb * 4];
            float w0 = sW[kk][tn * 2 + 0];
            float w1 = sW[kk][tn * 2 + 1];
            acc[0][0] += hv.x * w0; acc[0][1] += hv.x * w1;
            acc[1][0] += hv.y * w0; acc[1][1] += hv.y * w1;
            acc[2][0] += hv.z * w0; acc[2][1] += hv.z * w1;
            acc[3][0] += hv.w * w0; acc[3][1] += hv.w * w1;
        }
        __syncthreads();
    }
#pragma unroll
    for (int i = 0; i < 4; i++)
#pragma unroll
        for (int j = 0; j < 2; j++) {
            int b = tb * 4 + i;
            int n = n0 + tn * 2 + j;
            float v = acc[i][j];
            if (is_att) att2g[(size_t)b * AD + n] = v + bda[n];
            else {
                int d = n - AD;
                fg[(size_t)b * ED + d] = sigm(v + bfb[d]);
            }
        }
}

// ---------------------------------------------------------------------------
// kA2: per-b softmax: e = relu(att1+att2)·wf + bf ; alpha (ws) + masked out.
//      1024 threads: 16 waves, one att1 row per wave per iter (deep in-flight).
// ---------------------------------------------------------------------------
__global__ __launch_bounds__(1024) void kA2(const float* __restrict__ att2g,
                                            const float* __restrict__ att1,
                                            const float* __restrict__ wf,
                                            const float* __restrict__ bfv,
                                            const int* __restrict__ dlen,
                                            float* __restrict__ alpha,
                                            float* __restrict__ out, int t) {
    int b = blockIdx.x;
    int tid = threadIdx.x;
    __shared__ float sa2[AD];
    __shared__ float swf[AD];
    __shared__ float se[P];
    __shared__ float red[1024];

    if (tid < AD) {
        sa2[tid] = att2g[(size_t)b * AD + tid];
        swf[tid] = wf[tid];
    }
    __syncthreads();

    int w = tid >> 6, lane = tid & 63;
    float bf0 = bfv[0];
#pragma unroll 2
    for (int p = w; p < P; p += 16) {
        const float* row = att1 + ((size_t)b * P + p) * AD + lane * 8;
        float4 u0 = *(const float4*)row;
        float4 u1 = *(const float4*)(row + 4);
        float4 s0 = *(const float4*)&sa2[lane * 8];
        float4 s1 = *(const float4*)&sa2[lane * 8 + 4];
        float4 w0 = *(const float4*)&swf[lane * 8];
        float4 w1 = *(const float4*)&swf[lane * 8 + 4];
        float acc = fmaxf(u0.x + s0.x, 0.f) * w0.x + fmaxf(u0.y + s0.y, 0.f) * w0.y +
                    fmaxf(u0.z + s0.z, 0.f) * w0.z + fmaxf(u0.w + s0.w, 0.f) * w0.w +
                    fmaxf(u1.x + s1.x, 0.f) * w1.x + fmaxf(u1.y + s1.y, 0.f) * w1.y +
                    fmaxf(u1.z + s1.z, 0.f) * w1.z + fmaxf(u1.w + s1.w, 0.f) * w1.w;
#pragma unroll
        for (int m = 32; m >= 1; m >>= 1) acc += __shfl_xor(acc, m, 64);
        if (lane == 0) se[p] = acc + bf0;
    }
    __syncthreads();

    red[tid] = (tid < P) ? se[tid] : -1e30f;
    __syncthreads();
    for (int s = 512; s > 0; s >>= 1) {
        if (tid < s) red[tid] = fmaxf(red[tid], red[tid + s]);
        __syncthreads();
    }
    float mx = red[0];
    __syncthreads();
    float ex = (tid < P) ? expf(se[tid] - mx) : 0.f;
    red[tid] = ex;
    __syncthreads();
    for (int s = 512; s > 0; s >>= 1) {
        if (tid < s) red[tid] += red[tid + s];
        __syncthreads();
    }
    float inv = 1.0f / red[0];
    if (tid < P) {
        float a = ex * inv;
        alpha[(size_t)b * P + tid] = a;
        float m = (dlen[b] > t) ? 1.f : 0.f;
        out[AOFF + ((size_t)b * TD + t) * P + tid] = a * m;
    }
}

// ---------------------------------------------------------------------------
// kB: awe + xg = fg*awe, write K-major xT rows [300, 2348).
//     float4 along d, p split 4-ways across waves, LDS reduce.
//     grid (8, B): block covers 256 d's. ~8KB in flight per wave.
// ---------------------------------------------------------------------------
__global__ __launch_bounds__(256) void kB(const float* __restrict__ eo,
                                          const int* __restrict__ sidx,
                                          const float* __restrict__ alpha,
                                          const float* __restrict__ fg,
                                          float* __restrict__ xT) {
    int b = blockIdx.y, ch = blockIdx.x, tid = threadIdx.x;
    int pg = tid >> 6, lane = tid & 63;
    __shared__ float sal[P];
    __shared__ float part[4][260];
    if (tid < P) sal[tid] = alpha[(size_t)b * P + tid];
    __syncthreads();
    int d = ch * 256 + lane * 4;
    const float* base = eo + ((size_t)sidx[b] * P) * ED + d;
    float ax = 0.f, ay = 0.f, az = 0.f, aw = 0.f;
#pragma unroll 7
    for (int i = 0; i < 49; i++) {
        int p = pg + i * 4;
        float4 v = *(const float4*)(base + (size_t)p * ED);
        float a = sal[p];
        ax += v.x * a; ay += v.y * a; az += v.z * a; aw += v.w * a;
    }
    part[pg][lane * 4 + 0] = ax;
    part[pg][lane * 4 + 1] = ay;
    part[pg][lane * 4 + 2] = az;
    part[pg][lane * 4 + 3] = aw;
    __syncthreads();
    if (tid < 64) {
        int d0 = ch * 256 + tid * 4;
        float4 g = *(const float4*)(fg + (size_t)b * ED + d0);
        float s0 = part[0][tid * 4 + 0] + part[1][tid * 4 + 0] + part[2][tid * 4 + 0] + part[3][tid * 4 + 0];
        float s1 = part[0][tid * 4 + 1] + part[1][tid * 4 + 1] + part[2][tid * 4 + 1] + part[3][tid * 4 + 1];
        float s2 = part[0][tid * 4 + 2] + part[1][tid * 4 + 2] + part[2][tid * 4 + 2] + part[3][tid * 4 + 2];
        float s3 = part[0][tid * 4 + 3] + part[1][tid * 4 + 3] + part[2][tid * 4 + 3] + part[3][tid * 4 + 3];
        xT[(size_t)(E + d0 + 0) * B + b] = g.x * s0;
        xT[(size_t)(E + d0 + 1) * B + b] = g.y * s1;
        xT[(size_t)(E + d0 + 2) * B + b] = g.z * s2;
        xT[(size_t)(E + d0 + 3) * B + b] = g.w * s3;
    }
}

// ---------------------------------------------------------------------------
// kC: gates partial GEMM. grid 512 = 8 K-splits x 64 N-tiles(32 cols).
// ---------------------------------------------------------------------------
__global__ __launch_bounds__(256) void kC(const float* __restrict__ xT,
                                          const float* __restrict__ Wih,
                                          const float* __restrict__ Whh,
                                          float* __restrict__ part) {
    int bx = blockIdx.x;
    int ks = bx >> 6, nb = bx & 63;
    int n0 = nb * 32;
    int tid = threadIdx.x;
    int tb = tid & 15, tn = tid >> 4;
    __shared__ float sW[16][36];
    float acc[4][2] = {};
    int kbase = ks * KPER;

    for (int tile = 0; tile < 23; tile++) {
        int k0 = kbase + tile * 16;
        if (tid < 128) {
            int kk = tid >> 3, nn = (tid & 7) * 4;
            int kg = k0 + kk;
            float4 wv = make_float4(0.f, 0.f, 0.f, 0.f);
            if (kg < KX) wv = *(const float4*)&Wih[(size_t)kg * NG + n0 + nn];
            else if (kg < KTOT) wv = *(const float4*)&Whh[(size_t)(kg - KX) * NG + n0 + nn];
            *(float4*)&sW[kk][nn] = wv;
        }
        __syncthreads();
#pragma unroll
        for (int kk = 0; kk < 16; kk++) {
            int kg = k0 + kk;
            float4 xv = make_float4(0.f, 0.f, 0.f, 0.f);
            if (kg < KTOT) xv = *(const float4*)&xT[(size_t)kg * B + tb * 4];
            float w0 = sW[kk][tn * 2 + 0];
            float w1 = sW[kk][tn * 2 + 1];
            acc[0][0] += xv.x * w0; acc[0][1] += xv.x * w1;
            acc[1][0] += xv.y * w0; acc[1][1] += xv.y * w1;
            acc[2][0] += xv.z * w0; acc[2][1] += xv.z * w1;
            acc[3][0] += xv.w * w0; acc[3][1] += xv.w * w1;
        }
        __syncthreads();
    }
    float* pr = part + (size_t)ks * B * NG;
#pragma unroll
    for (int i = 0; i < 4; i++)
#pragma unroll
        for (int j = 0; j < 2; j++) {
            int b = tb * 4 + i, n = n0 + tn * 2 + j;
            pr[(size_t)b * NG + n] = acc[i][j];
        }
}

// ---------------------------------------------------------------------------
// kD: reduce partials + biases, LSTM cell, mask blend; write hseq[t] + xT h-rows
// ---------------------------------------------------------------------------
__global__ __launch_bounds__(256) void kD(const float* __restrict__ part,
                                          const float* __restrict__ bih,
                                          const float* __restrict__ bhh,
                                          const float* __restrict__ hprev,
                                          const float* __restrict__ cc,
                                          const int* __restrict__ dlen,
                                          float* __restrict__ hseq_t,
                                          float* __restrict__ cn,
                                          float* __restrict__ xT, int t) {
    int idx = blockIdx.x * 256 + threadIdx.x;  // B*DD
    int b = idx >> 9, j = idx & 511;
    float gi = bih[j] + bhh[j];
    float gf = bih[DD + j] + bhh[DD + j];
    float gg = bih[2 * DD + j] + bhh[2 * DD + j];
    float go = bih[3 * DD + j] + bhh[3 * DD + j];
#pragma unroll
    for (int s = 0; s < KSPLIT; s++) {
        const float* pr = part + ((size_t)s * B + b) * NG;
        gi += pr[j];
        gf += pr[DD + j];
        gg += pr[2 * DD + j];
        go += pr[3 * DD + j];
    }
    float cold = cc[idx], hold = hprev[idx];
    float cnew = sigm(gf) * cold + sigm(gi) * tanhf(gg);
    float hnew = sigm(go) * tanhf(cnew);
    bool m = dlen[b] > t;
    float h2 = m ? hnew : hold;
    float c2 = m ? cnew : cold;
    hseq_t[idx] = h2;
    cn[idx] = c2;
    xT[(size_t)(KX + j) * B + b] = h2;
}

// ---------------------------------------------------------------------------
// K4: batched preds GEMM: out[b,t,v] = mask * (hseq[t,b,:]@Wfc + bfc)
//     grid (95 t-tiles, 16 n-tiles of 64; N=1000 tail-guarded)
// ---------------------------------------------------------------------------
__global__ __launch_bounds__(256) void k_predsall(const float* __restrict__ hseq,
                                                  const float* __restrict__ Wfc,
                                                  const float* __restrict__ bfc,
                                                  const int* __restrict__ dlen,
                                                  float* __restrict__ out) {
    int t = blockIdx.x;
    int n0 = blockIdx.y * 64;
    int tid = threadIdx.x;
    int tx = tid & 15, ty = tid >> 4;
    __shared__ float sA[16][68];
    __shared__ float sB[16][68];
    float acc[4][4] = {};
    const float* A = hseq + (size_t)t * B * DD;

    for (int k0 = 0; k0 < DD; k0 += 16) {
        {
            int b = tid >> 2, q = tid & 3;
            float4 hv = *(const float4*)(A + (size_t)b * DD + k0 + q * 4);
            sA[q * 4 + 0][b] = hv.x;
            sA[q * 4 + 1][b] = hv.y;
            sA[q * 4 + 2][b] = hv.z;
            sA[q * 4 + 3][b] = hv.w;
        }
        {
            int kk = tid >> 4, nn = (tid & 15) * 4;
            int c = n0 + nn;
            const float* wrow = Wfc + (size_t)(k0 + kk) * V;
            float4 wv;
            if (c + 3 < V) wv = *(const float4*)(wrow + c);
            else {
                wv.x = (c + 0 < V) ? wrow[c + 0] : 0.f;
                wv.y = (c + 1 < V) ? wrow[c + 1] : 0.f;
                wv.z = (c + 2 < V) ? wrow[c + 2] : 0.f;
                wv.w = (c + 3 < V) ? wrow[c + 3] : 0.f;
            }
            *(float4*)&sB[kk][nn] = wv;
        }
        __syncthreads();
#pragma unroll
        for (int kk = 0; kk < 16; kk++) {
            float4 a4 = *(const float4*)&sA[kk][ty * 4];
            float4 b4 = *(const float4*)&sB[kk][tx * 4];
            float av_[4] = {a4.x, a4.y, a4.z, a4.w};
            float bv_[4] = {b4.x, b4.y, b4.z, b4.w};
#pragma unroll
            for (int i = 0; i < 4; i++)
#pragma unroll
                for (int j = 0; j < 4; j++) acc[i][j] += av_[i] * bv_[j];
        }
        __syncthreads();
    }
#pragma unroll
    for (int i = 0; i < 4; i++) {
        int b = ty * 4 + i;
        bool m = dlen[b] > t;
#pragma unroll
        for (int j = 0; j < 4; j++) {
            int n = n0 + tx * 4 + j;
            if (n < V)
                out[POFF + ((size_t)b * TD + t) * V + n] = m ? (acc[i][j] + bfc[n]) : 0.f;
        }
    }
}

// ---------------------------------------------------------------------------
extern "C" void kernel_launch(void* const* d_in, const int* in_sizes, int n_in,
                              void* d_out, int out_size, void* d_ws, size_t ws_size,
                              hipStream_t stream) {
    const float* eo    = (const float*)d_in[0];
    const int*   caps  = (const int*)d_in[1];
    const int*   lens  = (const int*)d_in[2];
    const float* emb   = (const float*)d_in[3];
    const float* Wea   = (const float*)d_in[4];
    const float* bea   = (const float*)d_in[5];
    const float* Wda   = (const float*)d_in[6];
    const float* bda   = (const float*)d_in[7];
    const float* wfull = (const float*)d_in[8];
    const float* bfull = (const float*)d_in[9];
    const float* Wih_  = (const float*)d_in[10];
    const float* bih_  = (const float*)d_in[11];
    const float* Wic   = (const float*)d_in[12];
    const float* bic   = (const float*)d_in[13];
    const float* Wfb   = (const float*)d_in[14];
    const float* bfb   = (const float*)d_in[15];
    const float* Wih   = (const float*)d_in[16];
    const float* bih   = (const float*)d_in[17];
    const float* Whh   = (const float*)d_in[18];
    const float* bhh   = (const float*)d_in[19];
    const float* Wfc   = (const float*)d_in[20];
    const float* bfc   = (const float*)d_in[21];
    float* out = (float*)d_out;

    char* w = (char*)d_ws;
    auto carve = [&](size_t bytes) -> void* {
        void* p = (void*)w;
        w += (bytes + 255) & ~(size_t)255;
        return p;
    };
    int* sidx      = (int*)carve(B * 4);
    int* dlen      = (int*)carve(B * 4);
    int* caps_s    = (int*)carve((size_t)B * T * 4);
    float* mean_eo = (float*)carve((size_t)B * ED * 4);
    float* h0      = (float*)carve((size_t)B * DD * 4);
    float* cb0     = (float*)carve((size_t)B * DD * 4);
    float* cb1     = (float*)carve((size_t)B * DD * 4);
    float* att1    = (float*)carve((size_t)B * P * AD * 4);
    float* alphaW  = (float*)carve((size_t)B * P * 4);
    float* att2g   = (float*)carve((size_t)B * AD * 4);
    float* fg      = (float*)carve((size_t)B * ED * 4);
    float* xT      = (float*)carve((size_t)KTOT * B * 4);
    float* part    = (float*)carve((size_t)KSPLIT * B * NG * 4);
    float* hseq    = (float*)carve((size_t)TD * B * DD * 4);
    float* cb[2] = {cb0, cb1};

    k_sort<<<1, 64, 0, stream>>>(lens, caps, sidx, dlen, caps_s, out);
    k_mean<<<dim3(ED / 256, B), 256, 0, stream>>>(eo, sidx, mean_eo);
    k_init<<<(B * DD) / 256, 256, 0, stream>>>(mean_eo, Wih_, bih_, Wic, bic, h0, cb0, xT);
    k_att1<<<dim3((B * P) / 64, AD / 64), 256, 0, stream>>>(eo, Wea, bea, sidx, att1);

    for (int t = 0; t < TD; t++) {
        const float* hprev = (t == 0) ? h0 : (hseq + (size_t)(t - 1) * B * DD);
        float* cc = cb[t & 1];
        float* cn = cb[(t + 1) & 1];
        kA1<<<85, 256, 0, stream>>>(hprev, Wda, bda, Wfb, bfb, emb, caps_s, att2g, fg, xT, t);
        kA2<<<64, 1024, 0, stream>>>(att2g, att1, wfull, bfull, dlen, alphaW, out, t);
        kB<<<dim3(8, B), 256, 0, stream>>>(eo, sidx, alphaW, fg, xT);
        kC<<<512, 256, 0, stream>>>(xT, Wih, Whh, part);
        kD<<<(B * DD) / 256, 256, 0, stream>>>(part, bih, bhh, hprev, cc, dlen,
                                               hseq + (size_t)t * B * DD, cn, xT, t);
    }
    k_predsall<<<dim3(TD, 16), 256, 0, stream>>>(hseq, Wfc, bfc, dlen, out);
}